// Round 1
// 567.219 us; speedup vs baseline: 1.0075x; 1.0075x over previous
//
#include <hip/hip_runtime.h>
#include <math.h>

#define BATCH 8
#define NHEAD 16
#define HDIM 128
#define DMODEL 2048
#define MAXBLK 64
#define BLKSZ 64
#define KVLEN 4096
#define NSPLIT 16
#define CHUNK (KVLEN / NSPLIT)   // 256
#define SCALE 0.08838834764831845f  // 1/sqrt(128)
// log2(10000)/64
#define L2T_64 0.20762050593046015f

// ---------------- QKV projection: qkv[m][b][col] = hs[b,:] . W_m[col,:] + b_m[col]
// grid 512 x 256. Wave handles 3 columns (of the 6144 q|k|v columns) for all 8 batches.
// Also zero-inits the attention accumulator (o_raw + Lsum = 16512 floats) so the
// attn kernel can atomicAdd into it (workspace is poisoned between iterations).
__global__ __launch_bounds__(256) void qkv_kernel(
    const float* __restrict__ hs,
    const float* __restrict__ Wq, const float* __restrict__ bq,
    const float* __restrict__ Wk, const float* __restrict__ bk,
    const float* __restrict__ Wv, const float* __restrict__ bv,
    float* __restrict__ qkv_out,
    float* __restrict__ o_raw /* [128*128 floats] followed by Lsum [128] */)
{
    {
        int gtid = blockIdx.x * 256 + threadIdx.x;
        if (gtid < BATCH * NHEAD * HDIM + BATCH * NHEAD)   // 16512
            o_raw[gtid] = 0.f;
    }

    __shared__ float hsl[BATCH * DMODEL];   // 64 KB -> 2 blocks/CU
    {
        const float4* hs4 = (const float4*)hs;
        float4* hsl4 = (float4*)hsl;
        for (int idx = threadIdx.x; idx < BATCH * DMODEL / 4; idx += 256)
            hsl4[idx] = hs4[idx];
    }
    __syncthreads();

    int wave = threadIdx.x >> 6;
    int lane = threadIdx.x & 63;
    int gw = blockIdx.x * 4 + wave;          // 0..2047
    int col0 = gw * 3;                        // 0..6141

    const float* Wc[3];
    const float* biasc[3];
    int clc[3], mc[3];
    #pragma unroll
    for (int c = 0; c < 3; ++c) {
        int col = col0 + c;
        int m = col >> 11;
        mc[c] = m; clc[c] = col & (DMODEL - 1);
        Wc[c]    = (m == 0) ? Wq : (m == 1) ? Wk : Wv;
        biasc[c] = (m == 0) ? bq : (m == 1) ? bk : bv;
    }

    float acc[3][BATCH];
    #pragma unroll
    for (int c = 0; c < 3; ++c)
        #pragma unroll
        for (int b = 0; b < BATCH; ++b) acc[c][b] = 0.f;

    #pragma unroll
    for (int it = 0; it < DMODEL / 256; ++it) {   // 8 iterations
        int k0 = it * 256 + lane * 4;
        float4 w[3];
        #pragma unroll
        for (int c = 0; c < 3; ++c)
            w[c] = *(const float4*)(Wc[c] + (size_t)clc[c] * DMODEL + k0);
        #pragma unroll
        for (int b = 0; b < BATCH; ++b) {
            float4 hv = *(const float4*)(hsl + b * DMODEL + k0);
            #pragma unroll
            for (int c = 0; c < 3; ++c)
                acc[c][b] += hv.x * w[c].x + hv.y * w[c].y + hv.z * w[c].z + hv.w * w[c].w;
        }
    }

    #pragma unroll
    for (int c = 0; c < 3; ++c) {
        #pragma unroll
        for (int b = 0; b < BATCH; ++b) {
            float r = acc[c][b];
            r += __shfl_xor(r, 32); r += __shfl_xor(r, 16); r += __shfl_xor(r, 8);
            r += __shfl_xor(r, 4);  r += __shfl_xor(r, 2);  r += __shfl_xor(r, 1);
            if (lane == 0)
                qkv_out[mc[c] * (BATCH * DMODEL) + b * DMODEL + clc[c]] = r + biasc[c][clc[c]];
        }
    }
}

// ---------------- Flash-decode attention, split-KV, fused RoPE, no-max softmax.
// grid (NSPLIT, B*H) x 256. Half-wave (32 lanes x float4) per position, 2 pos/wave/iter.
// Splits accumulate directly into o_raw/Lsum via atomicAdd (combine kernel eliminated).
__global__ __launch_bounds__(256) void attn_kernel(
    const float* __restrict__ qkv,
    const float* __restrict__ k_cache, const float* __restrict__ v_cache,
    const int* __restrict__ hist, const int* __restrict__ bofs,
    float* __restrict__ o_raw, float* __restrict__ Lsum)
{
    int split = blockIdx.x;
    int bh = blockIdx.y;
    int b = bh >> 4, h = bh & 15;
    int pos = hist[b];
    int start = split * CHUNK;
    if (start > pos) return;                 // inactive split: nothing to contribute
    int end = min(start + CHUNK, pos + 1);

    int tid = threadIdx.x;
    int w = tid >> 6;
    int lane = tid & 63;
    int half = lane >> 5;
    int l32 = lane & 31;

    const float* qp   = qkv + b * DMODEL + h * HDIM;
    const float* knew = qkv + BATCH * DMODEL + b * DMODEL + h * HDIM;
    const float* vnew = qkv + 2 * BATCH * DMODEL + b * DMODEL + h * HDIM;

    // ---- load q / k_new fragments (4 dims per lane) and apply RoPE in-register
    int dbase = l32 * 4;              // 0..124
    int fi = dbase & 63;              // freq index base (same for all 4 dims, no wrap)
    float sgn = (dbase < 64) ? -1.f : 1.f;
    float4 q4  = *(const float4*)(qp + dbase);
    float4 qo  = *(const float4*)(qp + (dbase ^ 64));
    float4 kn4 = *(const float4*)(knew + dbase);
    float4 kno = *(const float4*)(knew + (dbase ^ 64));
    float4 vn4 = *(const float4*)(vnew + dbase);
    float fpos = (float)pos;
    float cs[4], sn[4];
    #pragma unroll
    for (int j = 0; j < 4; ++j) {
        float inv = exp2f(-(float)(fi + j) * L2T_64);
        float f = fpos * inv;
        sn[j] = sinf(f);
        cs[j] = cosf(f);
    }
    q4.x = q4.x * cs[0] + sgn * qo.x * sn[0];
    q4.y = q4.y * cs[1] + sgn * qo.y * sn[1];
    q4.z = q4.z * cs[2] + sgn * qo.z * sn[2];
    q4.w = q4.w * cs[3] + sgn * qo.w * sn[3];
    kn4.x = kn4.x * cs[0] + sgn * kno.x * sn[0];
    kn4.y = kn4.y * cs[1] + sgn * kno.y * sn[1];
    kn4.z = kn4.z * cs[2] + sgn * kno.z * sn[2];
    kn4.w = kn4.w * cs[3] + sgn * kno.w * sn[3];
    // fold 1/sqrt(HD) into q
    q4.x *= SCALE; q4.y *= SCALE; q4.z *= SCALE; q4.w *= SCALE;

    float l_run = 0.f;
    float4 o_acc = make_float4(0.f, 0.f, 0.f, 0.f);

    int s0 = start + w * 2;           // wave-uniform base
    int sl_ = s0 + half;              // this lane's position

    float4 k4 = make_float4(0,0,0,0), v4 = make_float4(0,0,0,0);
    if (s0 < end) {
        int blk = bofs[b * MAXBLK + (sl_ >> 6)];
        size_t base = ((size_t)(blk * BLKSZ + (sl_ & 63)) * NHEAD + h) * HDIM + dbase;
        k4 = *(const float4*)(k_cache + base);
        v4 = *(const float4*)(v_cache + base);
        if (sl_ == pos) { k4 = kn4; v4 = vn4; }
    }
    while (s0 < end) {
        int sn0 = s0 + 8;
        int sln = sl_ + 8;
        float4 k4n = make_float4(0,0,0,0), v4n = make_float4(0,0,0,0);
        if (sn0 < end) {
            int blk = bofs[b * MAXBLK + (sln >> 6)];
            size_t base = ((size_t)(blk * BLKSZ + (sln & 63)) * NHEAD + h) * HDIM + dbase;
            k4n = *(const float4*)(k_cache + base);
            v4n = *(const float4*)(v_cache + base);
            if (sln == pos) { k4n = kn4; v4n = vn4; }
        }
        float d = q4.x * k4.x + q4.y * k4.y + q4.z * k4.z + q4.w * k4.w;
        d += __shfl_xor(d, 1); d += __shfl_xor(d, 2); d += __shfl_xor(d, 4);
        d += __shfl_xor(d, 8); d += __shfl_xor(d, 16);
        float p = (sl_ <= pos) ? __expf(d) : 0.f;
        l_run += p;
        o_acc.x += p * v4.x; o_acc.y += p * v4.y;
        o_acc.z += p * v4.z; o_acc.w += p * v4.w;
        k4 = k4n; v4 = v4n; s0 = sn0; sl_ = sln;
    }

    // combine halves (same dims, different positions)
    l_run  += __shfl_xor(l_run, 32);
    o_acc.x += __shfl_xor(o_acc.x, 32);
    o_acc.y += __shfl_xor(o_acc.y, 32);
    o_acc.z += __shfl_xor(o_acc.z, 32);
    o_acc.w += __shfl_xor(o_acc.w, 32);

    __shared__ float sacc[4][HDIM];
    __shared__ float slr[4];
    if (half == 0) *(float4*)&sacc[w][dbase] = o_acc;
    if (lane == 0) slr[w] = l_run;
    __syncthreads();

    if (tid < HDIM)
        atomicAdd(o_raw + bh * HDIM + tid,
                  sacc[0][tid] + sacc[1][tid] + sacc[2][tid] + sacc[3][tid]);
    if (tid == 0)
        atomicAdd(Lsum + bh, slr[0] + slr[1] + slr[2] + slr[3]);
}

// ---------------- Output projection (combine fused into staging). grid 256 x 256.
__global__ __launch_bounds__(256) void oproj_kernel(
    const float* __restrict__ o_raw, const float* __restrict__ Lsum,
    const float* __restrict__ Wo, const float* __restrict__ bo,
    float* __restrict__ out)
{
    __shared__ float ol[BATCH * DMODEL];   // 64 KB
    {
        const float4* o4 = (const float4*)o_raw;
        float4* ol4 = (float4*)ol;
        for (int idx = threadIdx.x; idx < BATCH * DMODEL / 4; idx += 256) {
            float4 v = o4[idx];
            float L = Lsum[idx >> 5];      // 32 float4 per (b,h) row of 128 floats
            v.x /= L; v.y /= L; v.z /= L; v.w /= L;
            ol4[idx] = v;
        }
    }
    __syncthreads();

    int wave = threadIdx.x >> 6;
    int lane = threadIdx.x & 63;
    int gw = blockIdx.x * 4 + wave;     // 0..1023
    int col0 = gw * 2;                  // 0..2046

    float acc[2][BATCH];
    #pragma unroll
    for (int c = 0; c < 2; ++c)
        #pragma unroll
        for (int b = 0; b < BATCH; ++b) acc[c][b] = 0.f;

    #pragma unroll
    for (int it = 0; it < DMODEL / 256; ++it) {
        int k0 = it * 256 + lane * 4;
        float4 w[2];
        #pragma unroll
        for (int c = 0; c < 2; ++c)
            w[c] = *(const float4*)(Wo + (size_t)(col0 + c) * DMODEL + k0);
        #pragma unroll
        for (int b = 0; b < BATCH; ++b) {
            float4 hv = *(const float4*)(ol + b * DMODEL + k0);
            #pragma unroll
            for (int c = 0; c < 2; ++c)
                acc[c][b] += hv.x * w[c].x + hv.y * w[c].y + hv.z * w[c].z + hv.w * w[c].w;
        }
    }

    #pragma unroll
    for (int c = 0; c < 2; ++c) {
        #pragma unroll
        for (int b = 0; b < BATCH; ++b) {
            float r = acc[c][b];
            r += __shfl_xor(r, 32); r += __shfl_xor(r, 16); r += __shfl_xor(r, 8);
            r += __shfl_xor(r, 4);  r += __shfl_xor(r, 2);  r += __shfl_xor(r, 1);
            if (lane == 0)
                out[b * DMODEL + col0 + c] = r + bo[col0 + c];
        }
    }
}

extern "C" void kernel_launch(void* const* d_in, const int* in_sizes, int n_in,
                              void* d_out, int out_size, void* d_ws, size_t ws_size,
                              hipStream_t stream) {
    const float* hs      = (const float*)d_in[0];
    const float* k_cache = (const float*)d_in[1];
    const float* v_cache = (const float*)d_in[2];
    const float* Wq      = (const float*)d_in[3];
    const float* bq      = (const float*)d_in[4];
    const float* Wk      = (const float*)d_in[5];
    const float* bk      = (const float*)d_in[6];
    const float* Wv      = (const float*)d_in[7];
    const float* bv      = (const float*)d_in[8];
    const float* Wo      = (const float*)d_in[9];
    const float* bo      = (const float*)d_in[10];
    const int*   hist    = (const int*)d_in[11];
    const int*   bofs    = (const int*)d_in[12];
    float* out = (float*)d_out;

    float* ws = (float*)d_ws;
    float* qkv   = ws;                          // 3*8*2048 = 49152 floats
    float* o_raw = ws + 49152;                  // 128*128  = 16384 floats
    float* Ls    = o_raw + BATCH * NHEAD * HDIM; // 128 floats (zeroed together with o_raw)

    qkv_kernel<<<512, 256, 0, stream>>>(hs, Wq, bq, Wk, bk, Wv, bv, qkv, o_raw);
    attn_kernel<<<dim3(NSPLIT, BATCH * NHEAD), 256, 0, stream>>>(qkv, k_cache, v_cache, hist, bofs, o_raw, Ls);
    oproj_kernel<<<256, 256, 0, stream>>>(o_raw, Ls, Wo, bo, out);
}

// Round 2
// 565.090 us; speedup vs baseline: 1.0113x; 1.0038x over previous
//
#include <hip/hip_runtime.h>
#include <math.h>

#define BATCH 8
#define NHEAD 16
#define HDIM 128
#define DMODEL 2048
#define MAXBLK 64
#define BLKSZ 64
#define KVLEN 4096
#define NSPLIT 32
#define CHUNK (KVLEN / NSPLIT)   // 128  (= 2 cache blocks of 64)
#define SCALE 0.08838834764831845f  // 1/sqrt(128)
// log2(10000)/64
#define L2T_64 0.20762050593046015f

// ---------------- QKV projection: qkv[m][b][col] = hs[b,:] . W_m[col,:] + b_m[col]
// grid 512 x 256. Wave handles 3 columns (of the 6144 q|k|v columns) for all 8 batches.
// Also zero-inits the attention accumulator (o_raw + Lsum = 16512 floats) so the
// attn kernel can atomicAdd into it (workspace is poisoned between iterations).
__global__ __launch_bounds__(256) void qkv_kernel(
    const float* __restrict__ hs,
    const float* __restrict__ Wq, const float* __restrict__ bq,
    const float* __restrict__ Wk, const float* __restrict__ bk,
    const float* __restrict__ Wv, const float* __restrict__ bv,
    float* __restrict__ qkv_out,
    float* __restrict__ o_raw /* [128*128 floats] followed by Lsum [128] */)
{
    {
        int gtid = blockIdx.x * 256 + threadIdx.x;
        if (gtid < BATCH * NHEAD * HDIM + BATCH * NHEAD)   // 16512
            o_raw[gtid] = 0.f;
    }

    __shared__ float hsl[BATCH * DMODEL];   // 64 KB -> 2 blocks/CU
    {
        const float4* hs4 = (const float4*)hs;
        float4* hsl4 = (float4*)hsl;
        for (int idx = threadIdx.x; idx < BATCH * DMODEL / 4; idx += 256)
            hsl4[idx] = hs4[idx];
    }
    __syncthreads();

    int wave = threadIdx.x >> 6;
    int lane = threadIdx.x & 63;
    int gw = blockIdx.x * 4 + wave;          // 0..2047
    int col0 = gw * 3;                        // 0..6141

    const float* Wc[3];
    const float* biasc[3];
    int clc[3], mc[3];
    #pragma unroll
    for (int c = 0; c < 3; ++c) {
        int col = col0 + c;
        int m = col >> 11;
        mc[c] = m; clc[c] = col & (DMODEL - 1);
        Wc[c]    = (m == 0) ? Wq : (m == 1) ? Wk : Wv;
        biasc[c] = (m == 0) ? bq : (m == 1) ? bk : bv;
    }

    float acc[3][BATCH];
    #pragma unroll
    for (int c = 0; c < 3; ++c)
        #pragma unroll
        for (int b = 0; b < BATCH; ++b) acc[c][b] = 0.f;

    #pragma unroll
    for (int it = 0; it < DMODEL / 256; ++it) {   // 8 iterations
        int k0 = it * 256 + lane * 4;
        float4 w[3];
        #pragma unroll
        for (int c = 0; c < 3; ++c)
            w[c] = *(const float4*)(Wc[c] + (size_t)clc[c] * DMODEL + k0);
        #pragma unroll
        for (int b = 0; b < BATCH; ++b) {
            float4 hv = *(const float4*)(hsl + b * DMODEL + k0);
            #pragma unroll
            for (int c = 0; c < 3; ++c)
                acc[c][b] += hv.x * w[c].x + hv.y * w[c].y + hv.z * w[c].z + hv.w * w[c].w;
        }
    }

    #pragma unroll
    for (int c = 0; c < 3; ++c) {
        #pragma unroll
        for (int b = 0; b < BATCH; ++b) {
            float r = acc[c][b];
            r += __shfl_xor(r, 32); r += __shfl_xor(r, 16); r += __shfl_xor(r, 8);
            r += __shfl_xor(r, 4);  r += __shfl_xor(r, 2);  r += __shfl_xor(r, 1);
            if (lane == 0)
                qkv_out[mc[c] * (BATCH * DMODEL) + b * DMODEL + clc[c]] = r + biasc[c][clc[c]];
        }
    }
}

// ---------------- Flash-decode attention, split-KV, fused RoPE, no-max softmax.
// grid (NSPLIT, B*H) x 256. Half-wave (32 lanes x float4) per position, 2 pos/wave/iter.
// Splits accumulate directly into o_raw/Lsum via atomicAdd.
// CHUNK=128 spans exactly 2 cache blocks -> both block IDs hoisted to registers,
// keeping the prefetch address chain pure ALU (no bofs load on the critical path).
__global__ __launch_bounds__(256) void attn_kernel(
    const float* __restrict__ qkv,
    const float* __restrict__ k_cache, const float* __restrict__ v_cache,
    const int* __restrict__ hist, const int* __restrict__ bofs,
    float* __restrict__ o_raw, float* __restrict__ Lsum)
{
    int split = blockIdx.x;
    int bh = blockIdx.y;
    int b = bh >> 4, h = bh & 15;
    int pos = hist[b];
    int start = split * CHUNK;
    if (start > pos) return;                 // inactive split: nothing to contribute
    int end = min(start + CHUNK, pos + 1);

    int tid = threadIdx.x;
    int w = tid >> 6;
    int lane = tid & 63;
    int half = lane >> 5;
    int l32 = lane & 31;

    // chunk spans cache blocks cb0, cb0+1 (start is 128-aligned, cb0 even)
    int cb0 = start >> 6;
    int blk0 = bofs[b * MAXBLK + cb0];
    int blk1 = bofs[b * MAXBLK + cb0 + 1];   // cb0+1 <= 63 always (start <= 3968)

    const float* qp   = qkv + b * DMODEL + h * HDIM;
    const float* knew = qkv + BATCH * DMODEL + b * DMODEL + h * HDIM;
    const float* vnew = qkv + 2 * BATCH * DMODEL + b * DMODEL + h * HDIM;

    // ---- load q / k_new fragments (4 dims per lane) and apply RoPE in-register
    int dbase = l32 * 4;              // 0..124
    int fi = dbase & 63;              // freq index base (same for all 4 dims, no wrap)
    float sgn = (dbase < 64) ? -1.f : 1.f;
    float4 q4  = *(const float4*)(qp + dbase);
    float4 qo  = *(const float4*)(qp + (dbase ^ 64));
    float4 kn4 = *(const float4*)(knew + dbase);
    float4 kno = *(const float4*)(knew + (dbase ^ 64));
    float4 vn4 = *(const float4*)(vnew + dbase);
    float fpos = (float)pos;
    float cs[4], sn[4];
    #pragma unroll
    for (int j = 0; j < 4; ++j) {
        float inv = exp2f(-(float)(fi + j) * L2T_64);
        float f = fpos * inv;
        sn[j] = sinf(f);
        cs[j] = cosf(f);
    }
    q4.x = q4.x * cs[0] + sgn * qo.x * sn[0];
    q4.y = q4.y * cs[1] + sgn * qo.y * sn[1];
    q4.z = q4.z * cs[2] + sgn * qo.z * sn[2];
    q4.w = q4.w * cs[3] + sgn * qo.w * sn[3];
    kn4.x = kn4.x * cs[0] + sgn * kno.x * sn[0];
    kn4.y = kn4.y * cs[1] + sgn * kno.y * sn[1];
    kn4.z = kn4.z * cs[2] + sgn * kno.z * sn[2];
    kn4.w = kn4.w * cs[3] + sgn * kno.w * sn[3];
    // fold 1/sqrt(HD) into q
    q4.x *= SCALE; q4.y *= SCALE; q4.z *= SCALE; q4.w *= SCALE;

    float l_run = 0.f;
    float4 o_acc = make_float4(0.f, 0.f, 0.f, 0.f);

    int s0 = start + w * 2;           // wave-uniform base
    int sl_ = s0 + half;              // this lane's position

    float4 k4 = make_float4(0,0,0,0), v4 = make_float4(0,0,0,0);
    if (s0 < end) {
        int blk = ((sl_ >> 6) & 1) ? blk1 : blk0;
        size_t base = ((size_t)(blk * BLKSZ + (sl_ & 63)) * NHEAD + h) * HDIM + dbase;
        k4 = *(const float4*)(k_cache + base);
        v4 = *(const float4*)(v_cache + base);
        if (sl_ == pos) { k4 = kn4; v4 = vn4; }
    }
    while (s0 < end) {
        int sn0 = s0 + 8;
        int sln = sl_ + 8;
        float4 k4n = make_float4(0,0,0,0), v4n = make_float4(0,0,0,0);
        if (sn0 < end) {
            int blk = ((sln >> 6) & 1) ? blk1 : blk0;
            size_t base = ((size_t)(blk * BLKSZ + (sln & 63)) * NHEAD + h) * HDIM + dbase;
            k4n = *(const float4*)(k_cache + base);
            v4n = *(const float4*)(v_cache + base);
            if (sln == pos) { k4n = kn4; v4n = vn4; }
        }
        float d = q4.x * k4.x + q4.y * k4.y + q4.z * k4.z + q4.w * k4.w;
        d += __shfl_xor(d, 1); d += __shfl_xor(d, 2); d += __shfl_xor(d, 4);
        d += __shfl_xor(d, 8); d += __shfl_xor(d, 16);
        float p = (sl_ <= pos) ? __expf(d) : 0.f;
        l_run += p;
        o_acc.x += p * v4.x; o_acc.y += p * v4.y;
        o_acc.z += p * v4.z; o_acc.w += p * v4.w;
        k4 = k4n; v4 = v4n; s0 = sn0; sl_ = sln;
    }

    // combine halves (same dims, different positions)
    l_run  += __shfl_xor(l_run, 32);
    o_acc.x += __shfl_xor(o_acc.x, 32);
    o_acc.y += __shfl_xor(o_acc.y, 32);
    o_acc.z += __shfl_xor(o_acc.z, 32);
    o_acc.w += __shfl_xor(o_acc.w, 32);

    __shared__ float sacc[4][HDIM];
    __shared__ float slr[4];
    if (half == 0) *(float4*)&sacc[w][dbase] = o_acc;
    if (lane == 0) slr[w] = l_run;
    __syncthreads();

    if (tid < HDIM)
        atomicAdd(o_raw + bh * HDIM + tid,
                  sacc[0][tid] + sacc[1][tid] + sacc[2][tid] + sacc[3][tid]);
    if (tid == 0)
        atomicAdd(Lsum + bh, slr[0] + slr[1] + slr[2] + slr[3]);
}

// ---------------- Output projection (combine fused into staging). grid 256 x 256.
__global__ __launch_bounds__(256) void oproj_kernel(
    const float* __restrict__ o_raw, const float* __restrict__ Lsum,
    const float* __restrict__ Wo, const float* __restrict__ bo,
    float* __restrict__ out)
{
    __shared__ float ol[BATCH * DMODEL];   // 64 KB
    {
        const float4* o4 = (const float4*)o_raw;
        float4* ol4 = (float4*)ol;
        for (int idx = threadIdx.x; idx < BATCH * DMODEL / 4; idx += 256) {
            float4 v = o4[idx];
            float L = Lsum[idx >> 5];      // 32 float4 per (b,h) row of 128 floats
            v.x /= L; v.y /= L; v.z /= L; v.w /= L;
            ol4[idx] = v;
        }
    }
    __syncthreads();

    int wave = threadIdx.x >> 6;
    int lane = threadIdx.x & 63;
    int gw = blockIdx.x * 4 + wave;     // 0..1023
    int col0 = gw * 2;                  // 0..2046

    float acc[2][BATCH];
    #pragma unroll
    for (int c = 0; c < 2; ++c)
        #pragma unroll
        for (int b = 0; b < BATCH; ++b) acc[c][b] = 0.f;

    #pragma unroll
    for (int it = 0; it < DMODEL / 256; ++it) {
        int k0 = it * 256 + lane * 4;
        float4 w[2];
        #pragma unroll
        for (int c = 0; c < 2; ++c)
            w[c] = *(const float4*)(Wo + (size_t)(col0 + c) * DMODEL + k0);
        #pragma unroll
        for (int b = 0; b < BATCH; ++b) {
            float4 hv = *(const float4*)(ol + b * DMODEL + k0);
            #pragma unroll
            for (int c = 0; c < 2; ++c)
                acc[c][b] += hv.x * w[c].x + hv.y * w[c].y + hv.z * w[c].z + hv.w * w[c].w;
        }
    }

    #pragma unroll
    for (int c = 0; c < 2; ++c) {
        #pragma unroll
        for (int b = 0; b < BATCH; ++b) {
            float r = acc[c][b];
            r += __shfl_xor(r, 32); r += __shfl_xor(r, 16); r += __shfl_xor(r, 8);
            r += __shfl_xor(r, 4);  r += __shfl_xor(r, 2);  r += __shfl_xor(r, 1);
            if (lane == 0)
                out[b * DMODEL + col0 + c] = r + bo[col0 + c];
        }
    }
}

extern "C" void kernel_launch(void* const* d_in, const int* in_sizes, int n_in,
                              void* d_out, int out_size, void* d_ws, size_t ws_size,
                              hipStream_t stream) {
    const float* hs      = (const float*)d_in[0];
    const float* k_cache = (const float*)d_in[1];
    const float* v_cache = (const float*)d_in[2];
    const float* Wq      = (const float*)d_in[3];
    const float* bq      = (const float*)d_in[4];
    const float* Wk      = (const float*)d_in[5];
    const float* bk      = (const float*)d_in[6];
    const float* Wv      = (const float*)d_in[7];
    const float* bv      = (const float*)d_in[8];
    const float* Wo      = (const float*)d_in[9];
    const float* bo      = (const float*)d_in[10];
    const int*   hist    = (const int*)d_in[11];
    const int*   bofs    = (const int*)d_in[12];
    float* out = (float*)d_out;

    float* ws = (float*)d_ws;
    float* qkv   = ws;                           // 3*8*2048 = 49152 floats
    float* o_raw = ws + 49152;                   // 128*128  = 16384 floats
    float* Ls    = o_raw + BATCH * NHEAD * HDIM; // 128 floats (zeroed together with o_raw)

    qkv_kernel<<<512, 256, 0, stream>>>(hs, Wq, bq, Wk, bk, Wv, bv, qkv, o_raw);
    attn_kernel<<<dim3(NSPLIT, BATCH * NHEAD), 256, 0, stream>>>(qkv, k_cache, v_cache, hist, bofs, o_raw, Ls);
    oproj_kernel<<<256, 256, 0, stream>>>(o_raw, Ls, Wo, bo, out);
}

// Round 3
// 562.834 us; speedup vs baseline: 1.0153x; 1.0040x over previous
//
#include <hip/hip_runtime.h>
#include <math.h>

#define BATCH 8
#define NHEAD 16
#define HDIM 128
#define DMODEL 2048
#define MAXBLK 64
#define BLKSZ 64
#define KVLEN 4096
#define NSPLIT 32
#define CHUNK (KVLEN / NSPLIT)   // 128  (= 2 cache blocks of 64)
#define SCALE 0.08838834764831845f  // 1/sqrt(128)
// log2(10000)/64
#define L2T_64 0.20762050593046015f

typedef float __attribute__((ext_vector_type(4))) f4v;
__device__ __forceinline__ float4 nt4(const float* p) {
    f4v v = __builtin_nontemporal_load((const f4v*)p);
    return make_float4(v.x, v.y, v.z, v.w);
}

// ---------------- QKV projection: qkv[m][b][col] = hs[b,:] . W_m[col,:] + b_m[col]
// grid 512 x 256. Wave handles 3 columns (of the 6144 q|k|v columns) for all 8 batches.
// Also zero-inits the attention accumulator (o_raw + Lsum = 16512 floats) so the
// attn kernel can atomicAdd into it (workspace is poisoned between iterations).
__global__ __launch_bounds__(256) void qkv_kernel(
    const float* __restrict__ hs,
    const float* __restrict__ Wq, const float* __restrict__ bq,
    const float* __restrict__ Wk, const float* __restrict__ bk,
    const float* __restrict__ Wv, const float* __restrict__ bv,
    float* __restrict__ qkv_out,
    float* __restrict__ o_raw /* [128*128 floats] followed by Lsum [128] */)
{
    {
        int gtid = blockIdx.x * 256 + threadIdx.x;
        if (gtid < BATCH * NHEAD * HDIM + BATCH * NHEAD)   // 16512
            o_raw[gtid] = 0.f;
    }

    __shared__ float hsl[BATCH * DMODEL];   // 64 KB -> 2 blocks/CU
    {
        const float4* hs4 = (const float4*)hs;
        float4* hsl4 = (float4*)hsl;
        for (int idx = threadIdx.x; idx < BATCH * DMODEL / 4; idx += 256)
            hsl4[idx] = hs4[idx];
    }
    __syncthreads();

    int wave = threadIdx.x >> 6;
    int lane = threadIdx.x & 63;
    int gw = blockIdx.x * 4 + wave;          // 0..2047
    int col0 = gw * 3;                        // 0..6141

    const float* Wc[3];
    const float* biasc[3];
    int clc[3], mc[3];
    #pragma unroll
    for (int c = 0; c < 3; ++c) {
        int col = col0 + c;
        int m = col >> 11;
        mc[c] = m; clc[c] = col & (DMODEL - 1);
        Wc[c]    = (m == 0) ? Wq : (m == 1) ? Wk : Wv;
        biasc[c] = (m == 0) ? bq : (m == 1) ? bk : bv;
    }

    float acc[3][BATCH];
    #pragma unroll
    for (int c = 0; c < 3; ++c)
        #pragma unroll
        for (int b = 0; b < BATCH; ++b) acc[c][b] = 0.f;

    #pragma unroll
    for (int it = 0; it < DMODEL / 256; ++it) {   // 8 iterations
        int k0 = it * 256 + lane * 4;
        float4 w[3];
        #pragma unroll
        for (int c = 0; c < 3; ++c)
            w[c] = *(const float4*)(Wc[c] + (size_t)clc[c] * DMODEL + k0);
        #pragma unroll
        for (int b = 0; b < BATCH; ++b) {
            float4 hv = *(const float4*)(hsl + b * DMODEL + k0);
            #pragma unroll
            for (int c = 0; c < 3; ++c)
                acc[c][b] += hv.x * w[c].x + hv.y * w[c].y + hv.z * w[c].z + hv.w * w[c].w;
        }
    }

    #pragma unroll
    for (int c = 0; c < 3; ++c) {
        #pragma unroll
        for (int b = 0; b < BATCH; ++b) {
            float r = acc[c][b];
            r += __shfl_xor(r, 32); r += __shfl_xor(r, 16); r += __shfl_xor(r, 8);
            r += __shfl_xor(r, 4);  r += __shfl_xor(r, 2);  r += __shfl_xor(r, 1);
            if (lane == 0)
                qkv_out[mc[c] * (BATCH * DMODEL) + b * DMODEL + clc[c]] = r + biasc[c][clc[c]];
        }
    }
}

// ---------------- Flash-decode attention, split-KV, fused RoPE, no-max softmax.
// grid (NSPLIT, B*H) x 256. 16-lane group per position (8 dims/lane, 2 float4),
// 4 positions/wave/iter, 16 positions/block/iter. Cached K needs no RoPE; only the
// new token's k/q are roped (once, at init). K/V streamed with nontemporal loads.
__global__ __launch_bounds__(256, 4) void attn_kernel(
    const float* __restrict__ qkv,
    const float* __restrict__ k_cache, const float* __restrict__ v_cache,
    const int* __restrict__ hist, const int* __restrict__ bofs,
    float* __restrict__ o_raw, float* __restrict__ Lsum)
{
    int split = blockIdx.x;
    int bh = blockIdx.y;
    int b = bh >> 4, h = bh & 15;
    int pos = hist[b];
    int start = split * CHUNK;
    if (start > pos) return;                 // inactive split
    int end = min(start + CHUNK, pos + 1);   // note: end-1 <= pos always

    int tid = threadIdx.x;
    int w = tid >> 6;          // wave 0..3
    int lane = tid & 63;
    int g = lane >> 4;         // position group 0..3
    int l16 = lane & 15;
    int dbase = l16 * 8;       // dims [dbase, dbase+8)

    // chunk spans cache blocks cb0, cb0+1 (start is 128-aligned)
    int cb0 = start >> 6;
    int blk0 = bofs[b * MAXBLK + cb0];
    int blk1 = bofs[b * MAXBLK + cb0 + 1];

    const float* qp   = qkv + b * DMODEL + h * HDIM;
    const float* knew = qkv + BATCH * DMODEL + b * DMODEL + h * HDIM;
    const float* vnew = qkv + 2 * BATCH * DMODEL + b * DMODEL + h * HDIM;

    // ---- roped q (scaled), roped k_new, v_new : 8 floats per lane
    float q8[8], kn8[8], vn8[8];
    {
        float4 a0 = *(const float4*)(qp + dbase);
        float4 a1 = *(const float4*)(qp + dbase + 4);
        float4 ap0 = *(const float4*)(qp + (dbase ^ 64));
        float4 ap1 = *(const float4*)(qp + (dbase ^ 64) + 4);
        float4 b0 = *(const float4*)(knew + dbase);
        float4 b1 = *(const float4*)(knew + dbase + 4);
        float4 bp0 = *(const float4*)(knew + (dbase ^ 64));
        float4 bp1 = *(const float4*)(knew + (dbase ^ 64) + 4);
        float4 v0 = *(const float4*)(vnew + dbase);
        float4 v1 = *(const float4*)(vnew + dbase + 4);
        float qa[8]    = {a0.x,a0.y,a0.z,a0.w,a1.x,a1.y,a1.z,a1.w};
        float qpair[8] = {ap0.x,ap0.y,ap0.z,ap0.w,ap1.x,ap1.y,ap1.z,ap1.w};
        float ka[8]    = {b0.x,b0.y,b0.z,b0.w,b1.x,b1.y,b1.z,b1.w};
        float kpair[8] = {bp0.x,bp0.y,bp0.z,bp0.w,bp1.x,bp1.y,bp1.z,bp1.w};
        vn8[0]=v0.x; vn8[1]=v0.y; vn8[2]=v0.z; vn8[3]=v0.w;
        vn8[4]=v1.x; vn8[5]=v1.y; vn8[6]=v1.z; vn8[7]=v1.w;
        float fpos = (float)pos;
        float sgn = (dbase < 64) ? -1.f : 1.f;
        #pragma unroll
        for (int j = 0; j < 8; ++j) {
            float fi = (float)((dbase & 63) + j);
            float inv = exp2f(-fi * L2T_64);
            float f = fpos * inv;
            float s = sinf(f), c = cosf(f);
            q8[j]  = (qa[j] * c + sgn * qpair[j] * s) * SCALE;
            kn8[j] = ka[j] * c + sgn * kpair[j] * s;
        }
    }

    float l_run = 0.f;
    float o_acc[8];
    #pragma unroll
    for (int j = 0; j < 8; ++j) o_acc[j] = 0.f;

    int S = start;                 // block-uniform iteration base (stride 16)
    int sl = start + w * 4 + g;    // this group's position

    float4 kc0 = make_float4(0,0,0,0), kc1 = kc0, vc0 = kc0, vc1 = kc0;
    if (sl < end) {
        int blk = ((sl >> 6) & 1) ? blk1 : blk0;
        size_t idx = ((size_t)(blk * BLKSZ + (sl & 63)) * NHEAD + h) * HDIM + dbase;
        kc0 = nt4(k_cache + idx); kc1 = nt4(k_cache + idx + 4);
        vc0 = nt4(v_cache + idx); vc1 = nt4(v_cache + idx + 4);
        if (sl == pos) {
            kc0 = make_float4(kn8[0],kn8[1],kn8[2],kn8[3]);
            kc1 = make_float4(kn8[4],kn8[5],kn8[6],kn8[7]);
            vc0 = make_float4(vn8[0],vn8[1],vn8[2],vn8[3]);
            vc1 = make_float4(vn8[4],vn8[5],vn8[6],vn8[7]);
        }
    }
    while (S < end) {
        int sl2 = sl + 16;
        float4 kd0 = make_float4(0,0,0,0), kd1 = kd0, vd0 = kd0, vd1 = kd0;
        if (sl2 < end) {
            int blk = ((sl2 >> 6) & 1) ? blk1 : blk0;
            size_t idx = ((size_t)(blk * BLKSZ + (sl2 & 63)) * NHEAD + h) * HDIM + dbase;
            kd0 = nt4(k_cache + idx); kd1 = nt4(k_cache + idx + 4);
            vd0 = nt4(v_cache + idx); vd1 = nt4(v_cache + idx + 4);
            if (sl2 == pos) {
                kd0 = make_float4(kn8[0],kn8[1],kn8[2],kn8[3]);
                kd1 = make_float4(kn8[4],kn8[5],kn8[6],kn8[7]);
                vd0 = make_float4(vn8[0],vn8[1],vn8[2],vn8[3]);
                vd1 = make_float4(vn8[4],vn8[5],vn8[6],vn8[7]);
            }
        }
        float d = q8[0]*kc0.x + q8[1]*kc0.y + q8[2]*kc0.z + q8[3]*kc0.w
                + q8[4]*kc1.x + q8[5]*kc1.y + q8[6]*kc1.z + q8[7]*kc1.w;
        d += __shfl_xor(d, 1); d += __shfl_xor(d, 2);
        d += __shfl_xor(d, 4); d += __shfl_xor(d, 8);
        float p = (sl < end) ? __expf(d) : 0.f;   // sl < end  <=>  sl <= pos
        l_run += p;
        o_acc[0] += p * vc0.x; o_acc[1] += p * vc0.y;
        o_acc[2] += p * vc0.z; o_acc[3] += p * vc0.w;
        o_acc[4] += p * vc1.x; o_acc[5] += p * vc1.y;
        o_acc[6] += p * vc1.z; o_acc[7] += p * vc1.w;
        kc0 = kd0; kc1 = kd1; vc0 = vd0; vc1 = vd1;
        S += 16; sl = sl2;
    }

    // sum across the 4 position-groups (same dims live at same l16)
    #pragma unroll
    for (int j = 0; j < 8; ++j) {
        o_acc[j] += __shfl_xor(o_acc[j], 16);
        o_acc[j] += __shfl_xor(o_acc[j], 32);
    }
    l_run += __shfl_xor(l_run, 16);
    l_run += __shfl_xor(l_run, 32);

    __shared__ float sacc[4][HDIM];
    __shared__ float slr[4];
    if (lane < 16) {
        *(float4*)&sacc[w][dbase]     = make_float4(o_acc[0],o_acc[1],o_acc[2],o_acc[3]);
        *(float4*)&sacc[w][dbase + 4] = make_float4(o_acc[4],o_acc[5],o_acc[6],o_acc[7]);
    }
    if (lane == 0) slr[w] = l_run;
    __syncthreads();

    if (tid < HDIM)
        atomicAdd(o_raw + bh * HDIM + tid,
                  sacc[0][tid] + sacc[1][tid] + sacc[2][tid] + sacc[3][tid]);
    if (tid == 0)
        atomicAdd(Lsum + bh, slr[0] + slr[1] + slr[2] + slr[3]);
}

// ---------------- Output projection (combine fused into staging). grid 256 x 256.
__global__ __launch_bounds__(256) void oproj_kernel(
    const float* __restrict__ o_raw, const float* __restrict__ Lsum,
    const float* __restrict__ Wo, const float* __restrict__ bo,
    float* __restrict__ out)
{
    __shared__ float ol[BATCH * DMODEL];   // 64 KB
    {
        const float4* o4 = (const float4*)o_raw;
        float4* ol4 = (float4*)ol;
        for (int idx = threadIdx.x; idx < BATCH * DMODEL / 4; idx += 256) {
            float4 v = o4[idx];
            float L = Lsum[idx >> 5];      // 32 float4 per (b,h) row of 128 floats
            v.x /= L; v.y /= L; v.z /= L; v.w /= L;
            ol4[idx] = v;
        }
    }
    __syncthreads();

    int wave = threadIdx.x >> 6;
    int lane = threadIdx.x & 63;
    int gw = blockIdx.x * 4 + wave;     // 0..1023
    int col0 = gw * 2;                  // 0..2046

    float acc[2][BATCH];
    #pragma unroll
    for (int c = 0; c < 2; ++c)
        #pragma unroll
        for (int b = 0; b < BATCH; ++b) acc[c][b] = 0.f;

    #pragma unroll
    for (int it = 0; it < DMODEL / 256; ++it) {
        int k0 = it * 256 + lane * 4;
        float4 w[2];
        #pragma unroll
        for (int c = 0; c < 2; ++c)
            w[c] = *(const float4*)(Wo + (size_t)(col0 + c) * DMODEL + k0);
        #pragma unroll
        for (int b = 0; b < BATCH; ++b) {
            float4 hv = *(const float4*)(ol + b * DMODEL + k0);
            #pragma unroll
            for (int c = 0; c < 2; ++c)
                acc[c][b] += hv.x * w[c].x + hv.y * w[c].y + hv.z * w[c].z + hv.w * w[c].w;
        }
    }

    #pragma unroll
    for (int c = 0; c < 2; ++c) {
        #pragma unroll
        for (int b = 0; b < BATCH; ++b) {
            float r = acc[c][b];
            r += __shfl_xor(r, 32); r += __shfl_xor(r, 16); r += __shfl_xor(r, 8);
            r += __shfl_xor(r, 4);  r += __shfl_xor(r, 2);  r += __shfl_xor(r, 1);
            if (lane == 0)
                out[b * DMODEL + col0 + c] = r + bo[col0 + c];
        }
    }
}

extern "C" void kernel_launch(void* const* d_in, const int* in_sizes, int n_in,
                              void* d_out, int out_size, void* d_ws, size_t ws_size,
                              hipStream_t stream) {
    const float* hs      = (const float*)d_in[0];
    const float* k_cache = (const float*)d_in[1];
    const float* v_cache = (const float*)d_in[2];
    const float* Wq      = (const float*)d_in[3];
    const float* bq      = (const float*)d_in[4];
    const float* Wk      = (const float*)d_in[5];
    const float* bk      = (const float*)d_in[6];
    const float* Wv      = (const float*)d_in[7];
    const float* bv      = (const float*)d_in[8];
    const float* Wo      = (const float*)d_in[9];
    const float* bo      = (const float*)d_in[10];
    const int*   hist    = (const int*)d_in[11];
    const int*   bofs    = (const int*)d_in[12];
    float* out = (float*)d_out;

    float* ws = (float*)d_ws;
    float* qkv   = ws;                           // 3*8*2048 = 49152 floats
    float* o_raw = ws + 49152;                   // 128*128  = 16384 floats
    float* Ls    = o_raw + BATCH * NHEAD * HDIM; // 128 floats (zeroed together with o_raw)

    qkv_kernel<<<512, 256, 0, stream>>>(hs, Wq, bq, Wk, bk, Wv, bv, qkv, o_raw);
    attn_kernel<<<dim3(NSPLIT, BATCH * NHEAD), 256, 0, stream>>>(qkv, k_cache, v_cache, hist, bofs, o_raw, Ls);
    oproj_kernel<<<256, 256, 0, stream>>>(o_raw, Ls, Wo, bo, out);
}